// Round 5
// baseline (4027.650 us; speedup 1.0000x reference)
//
#include <hip/hip_runtime.h>
#include <math.h>

#define S    612
#define SP   640          // padded state count (64 lanes x 10)
#define TT   8192
#define NB   32

// workspace layout (bytes)
#define WIN_OFF   0        // 640 float4 = 10240 B
#define IV_OFF    10240    // 4 floats
#define EMIS_OFF  16384    // 100*640 floats = 256000 B
#define OBS_OFF   272384   // 32*8192 ints = 1 MB  (16B aligned)

__global__ __launch_bounds__(256) void prep_tables(
    const float* __restrict__ tk, const float* __restrict__ ik,
    float* __restrict__ wIn2, float* __restrict__ Ivec)
{
    int i = blockIdx.x * 256 + threadIdx.x;
    if (i < S) {
        float l0 = tk[3*i], l1 = tk[3*i+1], l2 = tk[3*i+2], l3 = 1.0f;
        float m = fmaxf(fmaxf(l0, l1), fmaxf(l2, l3));
        float e0 = expf(l0-m), e1 = expf(l1-m), e2 = expf(l2-m), e3 = expf(l3-m);
        float inv = 1.0f / (e0+e1+e2+e3);
        wIn2[4*i + 0]              = e0*inv;
        wIn2[4*((i+1)%S) + 1]      = e1*inv;
        wIn2[4*((i+2)%S) + 2]      = e2*inv;
        wIn2[4*((i+3)%S) + 3]      = e3*inv;
    } else if (i < SP) {
        wIn2[4*i+0] = 0.f; wIn2[4*i+1] = 0.f; wIn2[4*i+2] = 0.f; wIn2[4*i+3] = 0.f;
    } else if (i == SP) {
        float l0 = ik[0], l1 = ik[1], l2 = ik[2], l3 = ik[3];
        float m = fmaxf(fmaxf(l0,l1), fmaxf(l2,l3));
        float e0 = expf(l0-m), e1 = expf(l1-m), e2 = expf(l2-m), e3 = expf(l3-m);
        float inv = 1.0f / (e0+e1+e2+e3);
        Ivec[0]=e0*inv; Ivec[1]=e1*inv; Ivec[2]=e2*inv; Ivec[3]=e3*inv;
    }
}

__global__ __launch_bounds__(256) void prep_emis(
    const float* __restrict__ ek, float* __restrict__ emisP)
{
    int tid = blockIdx.x * 256 + threadIdx.x;       // tid = o*SP + s
    if (tid >= 100*SP) return;
    int s = tid % SP;
    int o = tid / SP;
    float val = 0.0f;
    if (s < S-1) {
        int c = o >> 2, l = o & 3;
        if (c == 0) {
            val = 0.25f;
        } else {
            const float* g = ek + s*96 + (c-1)*4;
            float a0=g[0], a1=g[1], a2=g[2], a3=g[3];
            float m = fmaxf(fmaxf(a0,a1), fmaxf(a2,a3));
            float x0=expf(a0-m), x1=expf(a1-m), x2=expf(a2-m), x3=expf(a3-m);
            float inv = 1.0f/(x0+x1+x2+x3);
            float sel = (l==0)?x0:(l==1)?x1:(l==2)?x2:x3;
            val = sel * inv;
        }
    }
    emisP[tid] = val;
}

__global__ __launch_bounds__(256) void extract_obs(
    const float* __restrict__ x, int* __restrict__ obs)
{
    int row  = blockIdx.x * 4 + (threadIdx.x >> 6);
    int lane = threadIdx.x & 63;
    if (row >= NB*TT) return;
    const float* r = x + (size_t)row * 101;
    float acc = r[lane] * (float)lane;
    if (lane < 37) acc += r[64 + lane] * (float)(64 + lane);
    #pragma unroll
    for (int m = 32; m >= 1; m >>= 1) acc += __shfl_xor(acc, m, 64);
    if (lane == 0) obs[row] = (int)(acc + 0.5f);
}

// lane-shift-up-by-1 via DPP wave_shr:1 (VALU pipe); lane 0 -> 0
__device__ __forceinline__ float dpp_up1(float x) {
    int xi = __builtin_bit_cast(int, x);
    int r = __builtin_amdgcn_update_dpp(0, xi, 0x138, 0xF, 0xF, true);
    return __builtin_bit_cast(float, r);
}
__device__ __forceinline__ float rdlanef(float x, int lane) {
    return __builtin_bit_cast(float, __builtin_amdgcn_readlane(__builtin_bit_cast(int, x), lane));
}
__device__ __forceinline__ int rdlanei(int x, int lane) {
    return __builtin_amdgcn_readlane(x, lane);
}

// emission value K (0..9) of rotating buffer JB — all indices compile-time
#define EVQ(JB,K) (((K)&1) ? eb[JB][(K)>>1].y : eb[JB][(K)>>1].x)

// one HMM step consuming emission expressions E0..E9
#define HMM_CORE(E0,E1,E2,E3,E4,E5,E6,E7,E8,E9)                              \
  {                                                                          \
    float pm1 = dpp_up1(a[9]);                                               \
    float pm2 = dpp_up1(a[8]);                                               \
    float pm3 = dpp_up1(a[7]);                                               \
    float v609 = rdlanef(a[9], 60);                                          \
    float v610 = rdlanef(a[0], 61);                                          \
    float v611 = rdlanef(a[1], 61);                                          \
    pm1 = isl0 ? v611 : pm1;                                                 \
    pm2 = isl0 ? v610 : pm2;                                                 \
    pm3 = isl0 ? v609 : pm3;                                                 \
    float n3 = (E3)*(a[3]*w[3].x + a[2]*w[3].y + a[1]*w[3].z + a[0]*w[3].w); \
    float n4 = (E4)*(a[4]*w[4].x + a[3]*w[4].y + a[2]*w[4].z + a[1]*w[4].w); \
    float n5 = (E5)*(a[5]*w[5].x + a[4]*w[5].y + a[3]*w[5].z + a[2]*w[5].w); \
    float n6 = (E6)*(a[6]*w[6].x + a[5]*w[6].y + a[4]*w[6].z + a[3]*w[6].w); \
    float n7 = (E7)*(a[7]*w[7].x + a[6]*w[7].y + a[5]*w[7].z + a[4]*w[7].w); \
    float n8 = (E8)*(a[8]*w[8].x + a[7]*w[8].y + a[6]*w[8].z + a[5]*w[8].w); \
    float n9 = (E9)*(a[9]*w[9].x + a[8]*w[9].y + a[7]*w[9].z + a[6]*w[9].w); \
    float n0 = (E0)*(a[0]*w[0].x + pm1 *w[0].y + pm2 *w[0].z + pm3 *w[0].w); \
    float n1 = (E1)*(a[1]*w[1].x + a[0]*w[1].y + pm1 *w[1].z + pm2 *w[1].w); \
    float n2 = (E2)*(a[2]*w[2].x + a[1]*w[2].y + a[0]*w[2].z + pm1 *w[2].w); \
    a[0]=n0; a[1]=n1; a[2]=n2; a[3]=n3; a[4]=n4;                             \
    a[5]=n5; a[6]=n6; a[7]=n7; a[8]=n8; a[9]=n9;                             \
  }

#define HMM_STEP(JB) HMM_CORE(EVQ(JB,0),EVQ(JB,1),EVQ(JB,2),EVQ(JB,3),       \
                              EVQ(JB,4),EVQ(JB,5),EVQ(JB,6),EVQ(JB,7),       \
                              EVQ(JB,8),EVQ(JB,9))

// refill rotating buffer JB with emission row for uniform obs value OV
#define PREFETCH(JB, OV)                                                     \
  { int _oo = (OV);                                                          \
    const float2* _p = (const float2*)(emisP + _oo*SP + 10*l);               \
    eb[JB][0]=_p[0]; eb[JB][1]=_p[1]; eb[JB][2]=_p[2];                       \
    eb[JB][3]=_p[3]; eb[JB][4]=_p[4]; }

#define LOCSUM() (((a[0]+a[1])+(a[2]+a[3])) + ((a[4]+a[5])+(a[6]+a[7])) + (a[8]+a[9]))

// 8-step renorm group; O0..O7 are uniform obs values for prefetch targets t+4..t+11
#define GROUP(O0,O1,O2,O3,O4,O5,O6,O7)                                       \
    HMM_STEP(0); PREFETCH(0, O0);                                            \
    zl += __shfl_xor(zl, 32, 64);                                            \
    HMM_STEP(1); PREFETCH(1, O1);                                            \
    zl += __shfl_xor(zl, 16, 64);                                            \
    HMM_STEP(2); PREFETCH(2, O2);                                            \
    zl += __shfl_xor(zl, 8, 64);                                             \
    HMM_STEP(3); PREFETCH(3, O3);                                            \
    zl += __shfl_xor(zl, 4, 64);                                             \
    HMM_STEP(0); PREFETCH(0, O4);                                            \
    zl += __shfl_xor(zl, 2, 64);                                             \
    HMM_STEP(1); PREFETCH(1, O5);                                            \
    zl += __shfl_xor(zl, 1, 64);                                             \
    {                                                                        \
      float z   = zl;                                                        \
      float inv = __builtin_amdgcn_rcpf(z);                                  \
      float lg  = logf(z);                                                   \
      HMM_STEP(2); PREFETCH(2, O6);                                          \
      float ep[10];                                                          \
      _Pragma("unroll")                                                      \
      for (int k = 0; k < 10; ++k) ep[k] = EVQ(3,k) * inv;                   \
      HMM_CORE(ep[0],ep[1],ep[2],ep[3],ep[4],ep[5],ep[6],ep[7],ep[8],ep[9]);\
      PREFETCH(3, O7);                                                       \
      ll += lg;                                                              \
    }                                                                        \
    zl = LOCSUM();

// 8 waves per block, one batch per wave; no LDS, no barriers
__global__ __launch_bounds__(512) void forward(
    const float* __restrict__ emisP, const float4* __restrict__ wIn2,
    const float* __restrict__ Ivec, const int* __restrict__ obs,
    float* __restrict__ out)
{
    const int l  = threadIdx.x & 63;
    const int wv = threadIdx.x >> 6;
    const int b  = blockIdx.x * 8 + wv;
    const bool isl0 = (l == 0);
    const int* obp = obs + b * TT;

    float4 w[10];
    #pragma unroll
    for (int k = 0; k < 10; ++k) w[k] = wIn2[10*l + k];

    // obs ring: lane l of ovA holds obs[64k + l], ovB holds obs[64k+64 + l]
    int ovA = obp[l];
    int ovB = obp[64 + l];

    float a[10];
    float ll = 0.0f;

    // t = 0
    {
        int o0 = rdlanei(ovA, 0);
        const float* er = emisP + o0*SP + 10*l;
        #pragma unroll
        for (int k = 0; k < 10; ++k) {
            int s = 10*l + k;
            float Iv = (s < 4) ? Ivec[s] : 0.0f;
            a[k] = er[k] * Iv;
        }
    }
    float zl = LOCSUM();   // z_0 partial; butterfly runs inside first group

    // initial emission buffers: steps 1..4
    float2 eb[4][5];
    PREFETCH(0, rdlanei(ovA, 1));
    PREFETCH(1, rdlanei(ovA, 2));
    PREFETCH(2, rdlanei(ovA, 3));
    PREFETCH(3, rdlanei(ovA, 4));

    // superblocks: steps 64k+1 .. 64k+64, k = 0..126  (t = 1..8128)
    for (int kk = 0; kk < 127; ++kk) {
        int src = 64*kk + 128 + l;
        if (src >= TT) src = 0;            // clamped tail (value unused)
        int ovN = obp[src];
        #pragma unroll 1
        for (int j = 0; j < 7; ++j) {
            int base = 8*j + 5;
            GROUP(rdlanei(ovA,base  ), rdlanei(ovA,base+1),
                  rdlanei(ovA,base+2), rdlanei(ovA,base+3),
                  rdlanei(ovA,base+4), rdlanei(ovA,base+5),
                  rdlanei(ovA,base+6), rdlanei(ovA,base+7));
        }
        // j = 7 straddles the buffer boundary — compile-time lane indices
        GROUP(rdlanei(ovA,61), rdlanei(ovA,62), rdlanei(ovA,63),
              rdlanei(ovB,0),  rdlanei(ovB,1),  rdlanei(ovB,2),
              rdlanei(ovB,3),  rdlanei(ovB,4));
        ovA = ovB; ovB = ovN;
    }

    // epilogue groups: steps 8129..8184 (ovA covers [8128,8192))
    #pragma unroll 1
    for (int j = 0; j < 7; ++j) {
        int base = 8*j + 5;
        GROUP(rdlanei(ovA,base  ), rdlanei(ovA,base+1),
              rdlanei(ovA,base+2), rdlanei(ovA,base+3),
              rdlanei(ovA,base+4), rdlanei(ovA,base+5),
              rdlanei(ovA,base+6), rdlanei(ovA,base+7));
    }

    // final steps 8185..8191 (no renorm; final sum captures residual scale)
    HMM_STEP(0); PREFETCH(0, rdlanei(ovA,61));
    HMM_STEP(1); PREFETCH(1, rdlanei(ovA,62));
    HMM_STEP(2); PREFETCH(2, rdlanei(ovA,63));
    HMM_STEP(3);
    HMM_STEP(0);
    HMM_STEP(1);
    HMM_STEP(2);

    {
        float zf = LOCSUM();
        #pragma unroll
        for (int m = 32; m >= 1; m >>= 1) zf += __shfl_xor(zf, m, 64);
        ll += logf(zf);
    }
    if (isl0) out[b] = ll;
}

extern "C" void kernel_launch(void* const* d_in, const int* in_sizes, int n_in,
                              void* d_out, int out_size, void* d_ws, size_t ws_size,
                              hipStream_t stream)
{
    const float* x  = (const float*)d_in[0];   // inputs [32,8192,101]
    const float* ik = (const float*)d_in[1];   // init_kernel [4]
    const float* tk = (const float*)d_in[2];   // transition_kernel [1836]
    const float* ek = (const float*)d_in[3];   // emission_kernel [58656]
    float* out = (float*)d_out;

    char* ws = (char*)d_ws;
    float*  wIn2  = (float*)(ws + WIN_OFF);
    float*  Ivec  = (float*)(ws + IV_OFF);
    float*  emisP = (float*)(ws + EMIS_OFF);
    int*    obs   = (int*)(ws + OBS_OFF);

    hipLaunchKernelGGL(prep_tables, dim3(3), dim3(256), 0, stream, tk, ik, wIn2, Ivec);
    hipLaunchKernelGGL(prep_emis, dim3((100*SP + 255)/256), dim3(256), 0, stream, ek, emisP);
    hipLaunchKernelGGL(extract_obs, dim3((NB*TT + 3)/4), dim3(256), 0, stream, x, obs);
    hipLaunchKernelGGL(forward, dim3(4), dim3(512), 0, stream,
                       emisP, (const float4*)wIn2, Ivec, obs, out);
}

// Round 6
// 1477.669 us; speedup vs baseline: 2.7257x; 2.7257x over previous
//
#include <hip/hip_runtime.h>
#include <hip/hip_fp16.h>
#include <math.h>

#define S    612
#define SP   640          // padded state count (64 lanes x 10)
#define TT   8192
#define NB   32

// workspace layout (bytes)
#define WIN_OFF   0        // 640 float4 = 10240 B
#define IV_OFF    10240    // 4 floats
#define EMIS_OFF  16384    // 100*640 halves = 128000 B
#define OBS_OFF   272384   // 32*8192 ints = 1 MB  (16B aligned)

__global__ __launch_bounds__(256) void prep_tables(
    const float* __restrict__ tk, const float* __restrict__ ik,
    float* __restrict__ wIn2, float* __restrict__ Ivec)
{
    int i = blockIdx.x * 256 + threadIdx.x;
    if (i < S) {
        float l0 = tk[3*i], l1 = tk[3*i+1], l2 = tk[3*i+2], l3 = 1.0f;
        float m = fmaxf(fmaxf(l0, l1), fmaxf(l2, l3));
        float e0 = expf(l0-m), e1 = expf(l1-m), e2 = expf(l2-m), e3 = expf(l3-m);
        float inv = 1.0f / (e0+e1+e2+e3);
        wIn2[4*i + 0]              = e0*inv;
        wIn2[4*((i+1)%S) + 1]      = e1*inv;
        wIn2[4*((i+2)%S) + 2]      = e2*inv;
        wIn2[4*((i+3)%S) + 3]      = e3*inv;
    } else if (i < SP) {
        wIn2[4*i+0] = 0.f; wIn2[4*i+1] = 0.f; wIn2[4*i+2] = 0.f; wIn2[4*i+3] = 0.f;
    } else if (i == SP) {
        float l0 = ik[0], l1 = ik[1], l2 = ik[2], l3 = ik[3];
        float m = fmaxf(fmaxf(l0,l1), fmaxf(l2,l3));
        float e0 = expf(l0-m), e1 = expf(l1-m), e2 = expf(l2-m), e3 = expf(l3-m);
        float inv = 1.0f / (e0+e1+e2+e3);
        Ivec[0]=e0*inv; Ivec[1]=e1*inv; Ivec[2]=e2*inv; Ivec[3]=e3*inv;
    }
}

// emission table in fp16: emisH[o][s], s-fastest, padded to 640
__global__ __launch_bounds__(256) void prep_emis(
    const float* __restrict__ ek, unsigned short* __restrict__ emisH)
{
    int tid = blockIdx.x * 256 + threadIdx.x;       // tid = o*SP + s
    if (tid >= 100*SP) return;
    int s = tid % SP;
    int o = tid / SP;
    float val = 0.0f;
    if (s < S-1) {
        int c = o >> 2, l = o & 3;
        if (c == 0) {
            val = 0.25f;
        } else {
            const float* g = ek + s*96 + (c-1)*4;
            float a0=g[0], a1=g[1], a2=g[2], a3=g[3];
            float m = fmaxf(fmaxf(a0,a1), fmaxf(a2,a3));
            float x0=expf(a0-m), x1=expf(a1-m), x2=expf(a2-m), x3=expf(a3-m);
            float inv = 1.0f/(x0+x1+x2+x3);
            float sel = (l==0)?x0:(l==1)?x1:(l==2)?x2:x3;
            val = sel * inv;
        }
    }
    __half h = __float2half(val);
    emisH[tid] = *reinterpret_cast<unsigned short*>(&h);
}

__global__ __launch_bounds__(256) void extract_obs(
    const float* __restrict__ x, int* __restrict__ obs)
{
    int row  = blockIdx.x * 4 + (threadIdx.x >> 6);
    int lane = threadIdx.x & 63;
    if (row >= NB*TT) return;
    const float* r = x + (size_t)row * 101;
    float acc = r[lane] * (float)lane;
    if (lane < 37) acc += r[64 + lane] * (float)(64 + lane);
    #pragma unroll
    for (int m = 32; m >= 1; m >>= 1) acc += __shfl_xor(acc, m, 64);
    if (lane == 0) obs[row] = (int)(acc + 0.5f);
}

// lane-shift-up-by-1 via DPP wave_shr:1 (VALU pipe); lane 0 -> 0
__device__ __forceinline__ float dpp_up1(float x) {
    int xi = __builtin_bit_cast(int, x);
    int r = __builtin_amdgcn_update_dpp(0, xi, 0x138, 0xF, 0xF, true);
    return __builtin_bit_cast(float, r);
}
__device__ __forceinline__ float rdlanef(float x, int lane) {
    return __builtin_bit_cast(float, __builtin_amdgcn_readlane(__builtin_bit_cast(int, x), lane));
}
__device__ __forceinline__ int rdlanei(int x, int lane) {
    return __builtin_amdgcn_readlane(x, lane);
}
__device__ __forceinline__ float h2f_sel(unsigned int u, int hi) {
    unsigned short us = (unsigned short)(hi ? (u >> 16) : (u & 0xFFFF));
    __half h = *reinterpret_cast<__half*>(&us);
    return __half2float(h);
}

// emission value K (0..9) of rotating raw-half buffer JB — indices compile-time
#define EVQ(JB,K) h2f_sel(ebr[JB][(K)>>1], (K)&1)

// one HMM step consuming emission expressions E0..E9
#define HMM_CORE(E0,E1,E2,E3,E4,E5,E6,E7,E8,E9)                              \
  {                                                                          \
    float pm1 = dpp_up1(a[9]);                                               \
    float pm2 = dpp_up1(a[8]);                                               \
    float pm3 = dpp_up1(a[7]);                                               \
    float v609 = rdlanef(a[9], 60);                                          \
    float v610 = rdlanef(a[0], 61);                                          \
    float v611 = rdlanef(a[1], 61);                                          \
    pm1 = isl0 ? v611 : pm1;                                                 \
    pm2 = isl0 ? v610 : pm2;                                                 \
    pm3 = isl0 ? v609 : pm3;                                                 \
    float n3 = (E3)*(a[3]*w[3].x + a[2]*w[3].y + a[1]*w[3].z + a[0]*w[3].w); \
    float n4 = (E4)*(a[4]*w[4].x + a[3]*w[4].y + a[2]*w[4].z + a[1]*w[4].w); \
    float n5 = (E5)*(a[5]*w[5].x + a[4]*w[5].y + a[3]*w[5].z + a[2]*w[5].w); \
    float n6 = (E6)*(a[6]*w[6].x + a[5]*w[6].y + a[4]*w[6].z + a[3]*w[6].w); \
    float n7 = (E7)*(a[7]*w[7].x + a[6]*w[7].y + a[5]*w[7].z + a[4]*w[7].w); \
    float n8 = (E8)*(a[8]*w[8].x + a[7]*w[8].y + a[6]*w[8].z + a[5]*w[8].w); \
    float n9 = (E9)*(a[9]*w[9].x + a[8]*w[9].y + a[7]*w[9].z + a[6]*w[9].w); \
    float n0 = (E0)*(a[0]*w[0].x + pm1 *w[0].y + pm2 *w[0].z + pm3 *w[0].w); \
    float n1 = (E1)*(a[1]*w[1].x + a[0]*w[1].y + pm1 *w[1].z + pm2 *w[1].w); \
    float n2 = (E2)*(a[2]*w[2].x + a[1]*w[2].y + a[0]*w[2].z + pm1 *w[2].w); \
    a[0]=n0; a[1]=n1; a[2]=n2; a[3]=n3; a[4]=n4;                             \
    a[5]=n5; a[6]=n6; a[7]=n7; a[8]=n8; a[9]=n9;                             \
  }

#define HMM_STEP(JB) HMM_CORE(EVQ(JB,0),EVQ(JB,1),EVQ(JB,2),EVQ(JB,3),       \
                              EVQ(JB,4),EVQ(JB,5),EVQ(JB,6),EVQ(JB,7),       \
                              EVQ(JB,8),EVQ(JB,9))

// refill rotating buffer JB from the LDS fp16 table (5 x ds_read_b32, 2-way banks)
#define PREFETCH(JB, OV)                                                     \
  { int _oo = (OV);                                                          \
    const unsigned int* _p = eldu + _oo*(SP/2) + 5*l;                        \
    ebr[JB][0]=_p[0]; ebr[JB][1]=_p[1]; ebr[JB][2]=_p[2];                    \
    ebr[JB][3]=_p[3]; ebr[JB][4]=_p[4]; }

#define LOCSUM() (((a[0]+a[1])+(a[2]+a[3])) + ((a[4]+a[5])+(a[6]+a[7])) + (a[8]+a[9]))

// 8-step renorm group; O0..O7 are uniform obs values for prefetch targets t+4..t+11
#define GROUP(O0,O1,O2,O3,O4,O5,O6,O7)                                       \
    HMM_STEP(0); PREFETCH(0, O0);                                            \
    zl += __shfl_xor(zl, 32, 64);                                            \
    HMM_STEP(1); PREFETCH(1, O1);                                            \
    zl += __shfl_xor(zl, 16, 64);                                            \
    HMM_STEP(2); PREFETCH(2, O2);                                            \
    zl += __shfl_xor(zl, 8, 64);                                             \
    HMM_STEP(3); PREFETCH(3, O3);                                            \
    zl += __shfl_xor(zl, 4, 64);                                             \
    HMM_STEP(0); PREFETCH(0, O4);                                            \
    zl += __shfl_xor(zl, 2, 64);                                             \
    HMM_STEP(1); PREFETCH(1, O5);                                            \
    zl += __shfl_xor(zl, 1, 64);                                             \
    {                                                                        \
      float z   = zl;                                                        \
      float inv = __builtin_amdgcn_rcpf(z);                                  \
      float lg  = logf(z);                                                   \
      HMM_STEP(2); PREFETCH(2, O6);                                          \
      float ep[10];                                                          \
      _Pragma("unroll")                                                      \
      for (int k = 0; k < 10; ++k) ep[k] = EVQ(3,k) * inv;                   \
      HMM_CORE(ep[0],ep[1],ep[2],ep[3],ep[4],ep[5],ep[6],ep[7],ep[8],ep[9]);\
      PREFETCH(3, O7);                                                       \
      ll += lg;                                                              \
    }                                                                        \
    zl = LOCSUM();

// one wave per batch; whole fp16 emission table staged in LDS; no global loads
// on the step path
__global__ __launch_bounds__(64) void forward(
    const unsigned short* __restrict__ emisH, const float4* __restrict__ wIn2,
    const float* __restrict__ Ivec, const int* __restrict__ obs,
    float* __restrict__ out)
{
    __shared__ unsigned short eld[100*SP];   // 128000 B
    const int l = threadIdx.x;
    const int b = blockIdx.x;
    const bool isl0 = (l == 0);
    const int* obp = obs + b * TT;
    const unsigned int* eldu = (const unsigned int*)eld;

    // stage the table: 8000 uint4 = 125 iters of 64 lanes
    {
        const uint4* src = (const uint4*)emisH;
        uint4* dst = (uint4*)eld;
        for (int i = 0; i < 125; ++i) dst[l + 64*i] = src[l + 64*i];
    }
    __syncthreads();   // single wave: just a waitcnt; orders ds_write -> ds_read

    float4 w[10];
    #pragma unroll
    for (int k = 0; k < 10; ++k) w[k] = wIn2[10*l + k];

    // obs ring: lane l of ovA holds obs[64k + l], ovB holds obs[64k+64 + l]
    int ovA = obp[l];
    int ovB = obp[64 + l];

    float a[10];
    float ll = 0.0f;
    unsigned int ebr[4][5];

    // t = 0
    {
        int o0 = rdlanei(ovA, 0);
        const unsigned int* p = eldu + o0*(SP/2) + 5*l;
        unsigned int r0=p[0], r1=p[1], r2=p[2], r3=p[3], r4=p[4];
        float e0[10] = { h2f_sel(r0,0), h2f_sel(r0,1), h2f_sel(r1,0), h2f_sel(r1,1),
                         h2f_sel(r2,0), h2f_sel(r2,1), h2f_sel(r3,0), h2f_sel(r3,1),
                         h2f_sel(r4,0), h2f_sel(r4,1) };
        #pragma unroll
        for (int k = 0; k < 10; ++k) {
            int s = 10*l + k;
            float Iv = (s < 4) ? Ivec[s] : 0.0f;
            a[k] = e0[k] * Iv;
        }
    }
    float zl = LOCSUM();   // z_0 partial; butterfly runs inside first group

    // initial emission buffers: steps 1..4
    PREFETCH(0, rdlanei(ovA, 1));
    PREFETCH(1, rdlanei(ovA, 2));
    PREFETCH(2, rdlanei(ovA, 3));
    PREFETCH(3, rdlanei(ovA, 4));

    // superblocks: steps 64k+1 .. 64k+64, k = 0..126  (t = 1..8128)
    for (int kk = 0; kk < 127; ++kk) {
        int src = 64*kk + 128 + l;
        if (src >= TT) src = 0;            // clamped tail (value unused)
        int ovN = obp[src];
        #pragma unroll 1
        for (int j = 0; j < 7; ++j) {
            int base = 8*j + 5;
            GROUP(rdlanei(ovA,base  ), rdlanei(ovA,base+1),
                  rdlanei(ovA,base+2), rdlanei(ovA,base+3),
                  rdlanei(ovA,base+4), rdlanei(ovA,base+5),
                  rdlanei(ovA,base+6), rdlanei(ovA,base+7));
        }
        // j = 7 straddles the buffer boundary — compile-time lane indices
        GROUP(rdlanei(ovA,61), rdlanei(ovA,62), rdlanei(ovA,63),
              rdlanei(ovB,0),  rdlanei(ovB,1),  rdlanei(ovB,2),
              rdlanei(ovB,3),  rdlanei(ovB,4));
        ovA = ovB; ovB = ovN;
    }

    // epilogue groups: steps 8129..8184 (ovA covers [8128,8192))
    #pragma unroll 1
    for (int j = 0; j < 7; ++j) {
        int base = 8*j + 5;
        GROUP(rdlanei(ovA,base  ), rdlanei(ovA,base+1),
              rdlanei(ovA,base+2), rdlanei(ovA,base+3),
              rdlanei(ovA,base+4), rdlanei(ovA,base+5),
              rdlanei(ovA,base+6), rdlanei(ovA,base+7));
    }

    // final steps 8185..8191 (no renorm; final sum captures residual scale)
    HMM_STEP(0); PREFETCH(0, rdlanei(ovA,61));
    HMM_STEP(1); PREFETCH(1, rdlanei(ovA,62));
    HMM_STEP(2); PREFETCH(2, rdlanei(ovA,63));
    HMM_STEP(3);
    HMM_STEP(0);
    HMM_STEP(1);
    HMM_STEP(2);

    {
        float zf = LOCSUM();
        #pragma unroll
        for (int m = 32; m >= 1; m >>= 1) zf += __shfl_xor(zf, m, 64);
        ll += logf(zf);
    }
    if (isl0) out[b] = ll;
}

extern "C" void kernel_launch(void* const* d_in, const int* in_sizes, int n_in,
                              void* d_out, int out_size, void* d_ws, size_t ws_size,
                              hipStream_t stream)
{
    const float* x  = (const float*)d_in[0];   // inputs [32,8192,101]
    const float* ik = (const float*)d_in[1];   // init_kernel [4]
    const float* tk = (const float*)d_in[2];   // transition_kernel [1836]
    const float* ek = (const float*)d_in[3];   // emission_kernel [58656]
    float* out = (float*)d_out;

    char* ws = (char*)d_ws;
    float*          wIn2  = (float*)(ws + WIN_OFF);
    float*          Ivec  = (float*)(ws + IV_OFF);
    unsigned short* emisH = (unsigned short*)(ws + EMIS_OFF);
    int*            obs   = (int*)(ws + OBS_OFF);

    hipLaunchKernelGGL(prep_tables, dim3(3), dim3(256), 0, stream, tk, ik, wIn2, Ivec);
    hipLaunchKernelGGL(prep_emis, dim3((100*SP + 255)/256), dim3(256), 0, stream, ek, emisH);
    hipLaunchKernelGGL(extract_obs, dim3((NB*TT + 3)/4), dim3(256), 0, stream, x, obs);
    hipLaunchKernelGGL(forward, dim3(NB), dim3(64), 0, stream,
                       emisH, (const float4*)wIn2, Ivec, obs, out);
}

// Round 7
// 1433.898 us; speedup vs baseline: 2.8089x; 1.0305x over previous
//
#include <hip/hip_runtime.h>
#include <math.h>

#define S    612
#define SP   640          // padded state count (64 lanes x 10)
#define TT   8192
#define NB   32

// workspace layout (bytes)
#define WIN_OFF   0        // 640 float4 = 10240 B
#define IV_OFF    10240    // 4 floats
#define EMIS_OFF  16384    // 100*640 floats = 256000 B
#define OBS_OFF   272384   // 32*8192 ints = 1 MB  (16B aligned)

__global__ __launch_bounds__(256) void prep_tables(
    const float* __restrict__ tk, const float* __restrict__ ik,
    float* __restrict__ wIn2, float* __restrict__ Ivec)
{
    int i = blockIdx.x * 256 + threadIdx.x;
    if (i < S) {
        float l0 = tk[3*i], l1 = tk[3*i+1], l2 = tk[3*i+2], l3 = 1.0f;
        float m = fmaxf(fmaxf(l0, l1), fmaxf(l2, l3));
        float e0 = expf(l0-m), e1 = expf(l1-m), e2 = expf(l2-m), e3 = expf(l3-m);
        float inv = 1.0f / (e0+e1+e2+e3);
        wIn2[4*i + 0]              = e0*inv;
        wIn2[4*((i+1)%S) + 1]      = e1*inv;
        wIn2[4*((i+2)%S) + 2]      = e2*inv;
        wIn2[4*((i+3)%S) + 3]      = e3*inv;
    } else if (i < SP) {
        wIn2[4*i+0] = 0.f; wIn2[4*i+1] = 0.f; wIn2[4*i+2] = 0.f; wIn2[4*i+3] = 0.f;
    } else if (i == SP) {
        float l0 = ik[0], l1 = ik[1], l2 = ik[2], l3 = ik[3];
        float m = fmaxf(fmaxf(l0,l1), fmaxf(l2,l3));
        float e0 = expf(l0-m), e1 = expf(l1-m), e2 = expf(l2-m), e3 = expf(l3-m);
        float inv = 1.0f / (e0+e1+e2+e3);
        Ivec[0]=e0*inv; Ivec[1]=e1*inv; Ivec[2]=e2*inv; Ivec[3]=e3*inv;
    }
}

__global__ __launch_bounds__(256) void prep_emis(
    const float* __restrict__ ek, float* __restrict__ emisP)
{
    int tid = blockIdx.x * 256 + threadIdx.x;       // tid = o*SP + s
    if (tid >= 100*SP) return;
    int s = tid % SP;
    int o = tid / SP;
    float val = 0.0f;
    if (s < S-1) {
        int c = o >> 2, l = o & 3;
        if (c == 0) {
            val = 0.25f;
        } else {
            const float* g = ek + s*96 + (c-1)*4;
            float a0=g[0], a1=g[1], a2=g[2], a3=g[3];
            float m = fmaxf(fmaxf(a0,a1), fmaxf(a2,a3));
            float x0=expf(a0-m), x1=expf(a1-m), x2=expf(a2-m), x3=expf(a3-m);
            float inv = 1.0f/(x0+x1+x2+x3);
            float sel = (l==0)?x0:(l==1)?x1:(l==2)?x2:x3;
            val = sel * inv;
        }
    }
    emisP[tid] = val;
}

__global__ __launch_bounds__(256) void extract_obs(
    const float* __restrict__ x, int* __restrict__ obs)
{
    int row  = blockIdx.x * 4 + (threadIdx.x >> 6);
    int lane = threadIdx.x & 63;
    if (row >= NB*TT) return;
    const float* r = x + (size_t)row * 101;
    float acc = r[lane] * (float)lane;
    if (lane < 37) acc += r[64 + lane] * (float)(64 + lane);
    #pragma unroll
    for (int m = 32; m >= 1; m >>= 1) acc += __shfl_xor(acc, m, 64);
    if (lane == 0) obs[row] = (int)(acc + 0.5f);
}

// lane-shift-up-by-1 via DPP wave_shr:1 (VALU pipe); lane 0 -> 0
__device__ __forceinline__ float dpp_up1(float x) {
    int xi = __builtin_bit_cast(int, x);
    int r = __builtin_amdgcn_update_dpp(0, xi, 0x138, 0xF, 0xF, true);
    return __builtin_bit_cast(float, r);
}
// VALU-pipe reduction step: x + dpp(x); invalid source lanes contribute 0
template<int CTRL>
__device__ __forceinline__ float dpp_add(float x) {
    int sh = __builtin_amdgcn_update_dpp(0, __builtin_bit_cast(int, x), CTRL, 0xF, 0xF, true);
    return x + __builtin_bit_cast(float, sh);
}
__device__ __forceinline__ float rdlanef(float x, int lane) {
    return __builtin_bit_cast(float, __builtin_amdgcn_readlane(__builtin_bit_cast(int, x), lane));
}
__device__ __forceinline__ int rdlanei(int x, int lane) {
    return __builtin_amdgcn_readlane(x, lane);
}

// emission value K (0..9) of rotating buffer JB — all indices compile-time
#define EVQ(JB,K) (((K)&1) ? eb[JB][(K)>>1].y : eb[JB][(K)>>1].x)

// one HMM step consuming emission expressions E0..E9
#define HMM_CORE(E0,E1,E2,E3,E4,E5,E6,E7,E8,E9)                              \
  {                                                                          \
    float pm1 = dpp_up1(a[9]);                                               \
    float pm2 = dpp_up1(a[8]);                                               \
    float pm3 = dpp_up1(a[7]);                                               \
    float v609 = rdlanef(a[9], 60);                                          \
    float v610 = rdlanef(a[0], 61);                                          \
    float v611 = rdlanef(a[1], 61);                                          \
    pm1 = isl0 ? v611 : pm1;                                                 \
    pm2 = isl0 ? v610 : pm2;                                                 \
    pm3 = isl0 ? v609 : pm3;                                                 \
    float n3 = (E3)*(a[3]*w[3].x + a[2]*w[3].y + a[1]*w[3].z + a[0]*w[3].w); \
    float n4 = (E4)*(a[4]*w[4].x + a[3]*w[4].y + a[2]*w[4].z + a[1]*w[4].w); \
    float n5 = (E5)*(a[5]*w[5].x + a[4]*w[5].y + a[3]*w[5].z + a[2]*w[5].w); \
    float n6 = (E6)*(a[6]*w[6].x + a[5]*w[6].y + a[4]*w[6].z + a[3]*w[6].w); \
    float n7 = (E7)*(a[7]*w[7].x + a[6]*w[7].y + a[5]*w[7].z + a[4]*w[7].w); \
    float n8 = (E8)*(a[8]*w[8].x + a[7]*w[8].y + a[6]*w[8].z + a[5]*w[8].w); \
    float n9 = (E9)*(a[9]*w[9].x + a[8]*w[9].y + a[7]*w[9].z + a[6]*w[9].w); \
    float n0 = (E0)*(a[0]*w[0].x + pm1 *w[0].y + pm2 *w[0].z + pm3 *w[0].w); \
    float n1 = (E1)*(a[1]*w[1].x + a[0]*w[1].y + pm1 *w[1].z + pm2 *w[1].w); \
    float n2 = (E2)*(a[2]*w[2].x + a[1]*w[2].y + a[0]*w[2].z + pm1 *w[2].w); \
    a[0]=n0; a[1]=n1; a[2]=n2; a[3]=n3; a[4]=n4;                             \
    a[5]=n5; a[6]=n6; a[7]=n7; a[8]=n8; a[9]=n9;                             \
  }

#define HMM_STEP(JB) HMM_CORE(EVQ(JB,0),EVQ(JB,1),EVQ(JB,2),EVQ(JB,3),       \
                              EVQ(JB,4),EVQ(JB,5),EVQ(JB,6),EVQ(JB,7),       \
                              EVQ(JB,8),EVQ(JB,9))

// refill rotating buffer JB with emission row for uniform obs value OV (global/L2)
#define PREFETCH(JB, OV)                                                     \
  { int _oo = (OV);                                                          \
    const float2* _p = (const float2*)(emisP + _oo*SP + 10*l);               \
    eb[JB][0]=_p[0]; eb[JB][1]=_p[1]; eb[JB][2]=_p[2];                       \
    eb[JB][3]=_p[3]; eb[JB][4]=_p[4]; }

#define LOCSUM() (((a[0]+a[1])+(a[2]+a[3])) + ((a[4]+a[5])+(a[6]+a[7])) + (a[8]+a[9]))

// 8-step renorm group; z-reduction entirely on the VALU pipe (DPP), one stage
// per step: row_shr:1/2/4/8 then row_bcast:15/31 -> lane 63 holds the total.
#define GROUP(O0,O1,O2,O3,O4,O5,O6,O7)                                       \
    HMM_STEP(0); PREFETCH(0, O0);                                            \
    zl = dpp_add<0x111>(zl);                                                 \
    HMM_STEP(1); PREFETCH(1, O1);                                            \
    zl = dpp_add<0x112>(zl);                                                 \
    HMM_STEP(2); PREFETCH(2, O2);                                            \
    zl = dpp_add<0x114>(zl);                                                 \
    HMM_STEP(3); PREFETCH(3, O3);                                            \
    zl = dpp_add<0x118>(zl);                                                 \
    HMM_STEP(0); PREFETCH(0, O4);                                            \
    zl = dpp_add<0x142>(zl);                                                 \
    HMM_STEP(1); PREFETCH(1, O5);                                            \
    zl = dpp_add<0x143>(zl);                                                 \
    {                                                                        \
      float z   = rdlanef(zl, 63);                                           \
      float inv = __builtin_amdgcn_rcpf(z);                                  \
      float lg  = __logf(z);                                                 \
      HMM_STEP(2); PREFETCH(2, O6);                                          \
      float ep[10];                                                          \
      _Pragma("unroll")                                                      \
      for (int k = 0; k < 10; ++k) ep[k] = EVQ(3,k) * inv;                   \
      HMM_CORE(ep[0],ep[1],ep[2],ep[3],ep[4],ep[5],ep[6],ep[7],ep[8],ep[9]);\
      PREFETCH(3, O7);                                                       \
      ll += lg;                                                              \
    }                                                                        \
    zl = LOCSUM();

// one wave per batch; no LDS, no DS ops in the main loop
__global__ __launch_bounds__(64) void forward(
    const float* __restrict__ emisP, const float4* __restrict__ wIn2,
    const float* __restrict__ Ivec, const int* __restrict__ obs,
    float* __restrict__ out)
{
    const int l = threadIdx.x;
    const int b = blockIdx.x;
    const bool isl0 = (l == 0);
    const int* obp = obs + b * TT;

    float4 w[10];
    #pragma unroll
    for (int k = 0; k < 10; ++k) w[k] = wIn2[10*l + k];

    // obs ring: lane l of ovA holds obs[64k + l], ovB holds obs[64k+64 + l]
    int ovA = obp[l];
    int ovB = obp[64 + l];

    float a[10];
    float ll = 0.0f;
    float2 eb[4][5];

    // t = 0
    {
        int o0 = rdlanei(ovA, 0);
        const float2* p = (const float2*)(emisP + o0*SP + 10*l);
        float2 r0=p[0], r1=p[1], r2=p[2], r3=p[3], r4=p[4];
        float e0[10] = { r0.x,r0.y, r1.x,r1.y, r2.x,r2.y, r3.x,r3.y, r4.x,r4.y };
        #pragma unroll
        for (int k = 0; k < 10; ++k) {
            int s = 10*l + k;
            float Iv = (s < 4) ? Ivec[s] : 0.0f;
            a[k] = e0[k] * Iv;
        }
    }
    float zl = LOCSUM();   // z_0 partial; DPP tree runs inside first group

    // initial emission buffers: steps 1..4
    PREFETCH(0, rdlanei(ovA, 1));
    PREFETCH(1, rdlanei(ovA, 2));
    PREFETCH(2, rdlanei(ovA, 3));
    PREFETCH(3, rdlanei(ovA, 4));

    // superblocks: steps 64k+1 .. 64k+64, k = 0..126  (t = 1..8128)
    for (int kk = 0; kk < 127; ++kk) {
        int src = 64*kk + 128 + l;
        if (src >= TT) src = 0;            // clamped tail (value unused)
        int ovN = obp[src];
        #pragma unroll 1
        for (int j = 0; j < 7; ++j) {
            int base = 8*j + 5;
            GROUP(rdlanei(ovA,base  ), rdlanei(ovA,base+1),
                  rdlanei(ovA,base+2), rdlanei(ovA,base+3),
                  rdlanei(ovA,base+4), rdlanei(ovA,base+5),
                  rdlanei(ovA,base+6), rdlanei(ovA,base+7));
        }
        // j = 7 straddles the buffer boundary — compile-time lane indices
        GROUP(rdlanei(ovA,61), rdlanei(ovA,62), rdlanei(ovA,63),
              rdlanei(ovB,0),  rdlanei(ovB,1),  rdlanei(ovB,2),
              rdlanei(ovB,3),  rdlanei(ovB,4));
        ovA = ovB; ovB = ovN;
    }

    // epilogue groups: steps 8129..8184 (ovA covers [8128,8192))
    #pragma unroll 1
    for (int j = 0; j < 7; ++j) {
        int base = 8*j + 5;
        GROUP(rdlanei(ovA,base  ), rdlanei(ovA,base+1),
              rdlanei(ovA,base+2), rdlanei(ovA,base+3),
              rdlanei(ovA,base+4), rdlanei(ovA,base+5),
              rdlanei(ovA,base+6), rdlanei(ovA,base+7));
    }

    // final steps 8185..8191 (no renorm; final sum captures residual scale)
    HMM_STEP(0); PREFETCH(0, rdlanei(ovA,61));
    HMM_STEP(1); PREFETCH(1, rdlanei(ovA,62));
    HMM_STEP(2); PREFETCH(2, rdlanei(ovA,63));
    HMM_STEP(3);
    HMM_STEP(0);
    HMM_STEP(1);
    HMM_STEP(2);

    {
        float zf = LOCSUM();
        zf = dpp_add<0x111>(zf);
        zf = dpp_add<0x112>(zf);
        zf = dpp_add<0x114>(zf);
        zf = dpp_add<0x118>(zf);
        zf = dpp_add<0x142>(zf);
        zf = dpp_add<0x143>(zf);
        ll += __logf(rdlanef(zf, 63));
    }
    if (isl0) out[b] = ll;
}

extern "C" void kernel_launch(void* const* d_in, const int* in_sizes, int n_in,
                              void* d_out, int out_size, void* d_ws, size_t ws_size,
                              hipStream_t stream)
{
    const float* x  = (const float*)d_in[0];   // inputs [32,8192,101]
    const float* ik = (const float*)d_in[1];   // init_kernel [4]
    const float* tk = (const float*)d_in[2];   // transition_kernel [1836]
    const float* ek = (const float*)d_in[3];   // emission_kernel [58656]
    float* out = (float*)d_out;

    char* ws = (char*)d_ws;
    float*  wIn2  = (float*)(ws + WIN_OFF);
    float*  Ivec  = (float*)(ws + IV_OFF);
    float*  emisP = (float*)(ws + EMIS_OFF);
    int*    obs   = (int*)(ws + OBS_OFF);

    hipLaunchKernelGGL(prep_tables, dim3(3), dim3(256), 0, stream, tk, ik, wIn2, Ivec);
    hipLaunchKernelGGL(prep_emis, dim3((100*SP + 255)/256), dim3(256), 0, stream, ek, emisP);
    hipLaunchKernelGGL(extract_obs, dim3((NB*TT + 3)/4), dim3(256), 0, stream, x, obs);
    hipLaunchKernelGGL(forward, dim3(NB), dim3(64), 0, stream,
                       emisP, (const float4*)wIn2, Ivec, obs, out);
}

// Round 8
// 1027.159 us; speedup vs baseline: 3.9212x; 1.3960x over previous
//
#include <hip/hip_runtime.h>
#include <math.h>

#define S    612
#define SP   640          // padded state count (64 lanes x 10)
#define TT   8192
#define NB   32

// workspace layout (bytes)
#define WIN_OFF   0        // 640 float4 = 10240 B
#define IV_OFF    10240    // 4 floats
#define EMIS_OFF  16384    // 100*640 floats = 256000 B (pair-reordered)
#define OBS_OFF   272384   // 32*8192 ints = 1 MB  (16B aligned)

__global__ __launch_bounds__(256) void prep_tables(
    const float* __restrict__ tk, const float* __restrict__ ik,
    float* __restrict__ wIn2, float* __restrict__ Ivec)
{
    int i = blockIdx.x * 256 + threadIdx.x;
    if (i < S) {
        float l0 = tk[3*i], l1 = tk[3*i+1], l2 = tk[3*i+2], l3 = 1.0f;
        float m = fmaxf(fmaxf(l0, l1), fmaxf(l2, l3));
        float e0 = expf(l0-m), e1 = expf(l1-m), e2 = expf(l2-m), e3 = expf(l3-m);
        float inv = 1.0f / (e0+e1+e2+e3);
        wIn2[4*i + 0]              = e0*inv;
        wIn2[4*((i+1)%S) + 1]      = e1*inv;
        wIn2[4*((i+2)%S) + 2]      = e2*inv;
        wIn2[4*((i+3)%S) + 3]      = e3*inv;
    } else if (i < SP) {
        wIn2[4*i+0] = 0.f; wIn2[4*i+1] = 0.f; wIn2[4*i+2] = 0.f; wIn2[4*i+3] = 0.f;
    } else if (i == SP) {
        float l0 = ik[0], l1 = ik[1], l2 = ik[2], l3 = ik[3];
        float m = fmaxf(fmaxf(l0,l1), fmaxf(l2,l3));
        float e0 = expf(l0-m), e1 = expf(l1-m), e2 = expf(l2-m), e3 = expf(l3-m);
        float inv = 1.0f / (e0+e1+e2+e3);
        Ivec[0]=e0*inv; Ivec[1]=e1*inv; Ivec[2]=e2*inv; Ivec[3]=e3*inv;
    }
}

// emission table, stride-5 pair-reordered: row o holds, per lane l, five float2
// pairs (e[10l+j], e[10l+j+5]) at floats [o*SP + 10l + 2j {+1}]
__global__ __launch_bounds__(256) void prep_emis(
    const float* __restrict__ ek, float* __restrict__ emisP)
{
    int tid = blockIdx.x * 256 + threadIdx.x;       // tid = o*SP + s
    if (tid >= 100*SP) return;
    int s = tid % SP;
    int o = tid / SP;
    float val = 0.0f;
    if (s < S-1) {
        int c = o >> 2, l = o & 3;
        if (c == 0) {
            val = 0.25f;
        } else {
            const float* g = ek + s*96 + (c-1)*4;
            float a0=g[0], a1=g[1], a2=g[2], a3=g[3];
            float m = fmaxf(fmaxf(a0,a1), fmaxf(a2,a3));
            float x0=expf(a0-m), x1=expf(a1-m), x2=expf(a2-m), x3=expf(a3-m);
            float inv = 1.0f/(x0+x1+x2+x3);
            float sel = (l==0)?x0:(l==1)?x1:(l==2)?x2:x3;
            val = sel * inv;
        }
    }
    int ln = s / 10, j = s % 10;
    int pos = o*SP + ln*10 + ((j < 5) ? 2*j : 2*(j-5)+1);
    emisP[pos] = val;
}

__global__ __launch_bounds__(256) void extract_obs(
    const float* __restrict__ x, int* __restrict__ obs)
{
    int row  = blockIdx.x * 4 + (threadIdx.x >> 6);
    int lane = threadIdx.x & 63;
    if (row >= NB*TT) return;
    const float* r = x + (size_t)row * 101;
    float acc = r[lane] * (float)lane;
    if (lane < 37) acc += r[64 + lane] * (float)(64 + lane);
    #pragma unroll
    for (int m = 32; m >= 1; m >>= 1) acc += __shfl_xor(acc, m, 64);
    if (lane == 0) obs[row] = (int)(acc + 0.5f);
}

// lane-shift-up-by-1 via DPP wave_shr:1 (VALU pipe); lane 0 -> 0
__device__ __forceinline__ float dpp_up1(float x) {
    int xi = __builtin_bit_cast(int, x);
    int r = __builtin_amdgcn_update_dpp(0, xi, 0x138, 0xF, 0xF, true);
    return __builtin_bit_cast(float, r);
}
template<int CTRL>
__device__ __forceinline__ float dpp_add(float x) {
    int sh = __builtin_amdgcn_update_dpp(0, __builtin_bit_cast(int, x), CTRL, 0xF, 0xF, true);
    return x + __builtin_bit_cast(float, sh);
}
__device__ __forceinline__ float rdlanef(float x, int lane) {
    return __builtin_bit_cast(float, __builtin_amdgcn_readlane(__builtin_bit_cast(int, x), lane));
}
__device__ __forceinline__ int rdlanei(int x, int lane) {
    return __builtin_amdgcn_readlane(x, lane);
}
// packed f32 math (VOP3P, full-rate on CDNA): 2 FLOPs/lane/inst
__device__ __forceinline__ float2 pk_mul(float2 a, float2 b) {
    float2 d;
    asm("v_pk_mul_f32 %0, %1, %2" : "=v"(d) : "v"(a), "v"(b));
    return d;
}
__device__ __forceinline__ float2 pk_fma(float2 a, float2 b, float2 c) {
    float2 d;
    asm("v_pk_fma_f32 %0, %1, %2, %3" : "=v"(d) : "v"(a), "v"(b), "v"(c));
    return d;
}

// one HMM step, stride-5 packed pairs p[j] = (a_j, a_{j+5}); E0..E4 are
// emission pairs. Shift-m operand at pair j is p[j-m]; boundary pairs
// B1=(pm1,a4), B2=(pm2,a3), B3=(pm3,a2) are shared across shifts.
#define HMM_COREP(E0,E1,E2,E3,E4)                                            \
  {                                                                          \
    float pm1 = dpp_up1(p[4].y);            /* a9 of lane-1 */               \
    float pm2 = dpp_up1(p[3].y);            /* a8 of lane-1 */               \
    float pm3 = dpp_up1(p[2].y);            /* a7 of lane-1 */               \
    float v609 = rdlanef(p[4].y, 60);                                        \
    float v610 = rdlanef(p[0].x, 61);                                        \
    float v611 = rdlanef(p[1].x, 61);                                        \
    pm1 = isl0 ? v611 : pm1;                                                 \
    pm2 = isl0 ? v610 : pm2;                                                 \
    pm3 = isl0 ? v609 : pm3;                                                 \
    float2 B1 = make_float2(pm1, p[4].x);                                    \
    float2 B2 = make_float2(pm2, p[3].x);                                    \
    float2 B3 = make_float2(pm3, p[2].x);                                    \
    float2 c0 = pk_mul(p[0], W[0][0]);                                       \
    c0 = pk_fma(B1,   W[0][1], c0);                                          \
    c0 = pk_fma(B2,   W[0][2], c0);                                          \
    c0 = pk_fma(B3,   W[0][3], c0);                                          \
    float2 n0 = pk_mul(c0, (E0));                                            \
    float2 c1 = pk_mul(p[1], W[1][0]);                                       \
    c1 = pk_fma(p[0], W[1][1], c1);                                          \
    c1 = pk_fma(B1,   W[1][2], c1);                                          \
    c1 = pk_fma(B2,   W[1][3], c1);                                          \
    float2 n1 = pk_mul(c1, (E1));                                            \
    float2 c2 = pk_mul(p[2], W[2][0]);                                       \
    c2 = pk_fma(p[1], W[2][1], c2);                                          \
    c2 = pk_fma(p[0], W[2][2], c2);                                          \
    c2 = pk_fma(B1,   W[2][3], c2);                                          \
    float2 n2 = pk_mul(c2, (E2));                                            \
    float2 c3 = pk_mul(p[3], W[3][0]);                                       \
    c3 = pk_fma(p[2], W[3][1], c3);                                          \
    c3 = pk_fma(p[1], W[3][2], c3);                                          \
    c3 = pk_fma(p[0], W[3][3], c3);                                          \
    float2 n3 = pk_mul(c3, (E3));                                            \
    float2 c4 = pk_mul(p[4], W[4][0]);                                       \
    c4 = pk_fma(p[3], W[4][1], c4);                                          \
    c4 = pk_fma(p[2], W[4][2], c4);                                          \
    c4 = pk_fma(p[1], W[4][3], c4);                                          \
    float2 n4 = pk_mul(c4, (E4));                                            \
    p[0]=n0; p[1]=n1; p[2]=n2; p[3]=n3; p[4]=n4;                             \
  }

#define HMM_STEPP(JB) HMM_COREP(eb[JB][0],eb[JB][1],eb[JB][2],eb[JB][3],eb[JB][4])

// refill rotating buffer JB with (pair-reordered) emission row for obs OV
#define PREFETCH(JB, OV)                                                     \
  { int _oo = (OV);                                                          \
    const float2* _p = (const float2*)(emisP + _oo*SP + 10*l);               \
    eb[JB][0]=_p[0]; eb[JB][1]=_p[1]; eb[JB][2]=_p[2];                       \
    eb[JB][3]=_p[3]; eb[JB][4]=_p[4]; }

#define LOCSUM() (((p[0].x+p[0].y)+(p[1].x+p[1].y)) +                        \
                  ((p[2].x+p[2].y)+(p[3].x+p[3].y)) + (p[4].x+p[4].y))

// 8-step renorm group; z-reduction on the VALU pipe (DPP), one stage per step
#define GROUP(O0,O1,O2,O3,O4,O5,O6,O7)                                       \
    HMM_STEPP(0); PREFETCH(0, O0);                                           \
    zl = dpp_add<0x111>(zl);                                                 \
    HMM_STEPP(1); PREFETCH(1, O1);                                           \
    zl = dpp_add<0x112>(zl);                                                 \
    HMM_STEPP(2); PREFETCH(2, O2);                                           \
    zl = dpp_add<0x114>(zl);                                                 \
    HMM_STEPP(3); PREFETCH(3, O3);                                           \
    zl = dpp_add<0x118>(zl);                                                 \
    HMM_STEPP(0); PREFETCH(0, O4);                                           \
    zl = dpp_add<0x142>(zl);                                                 \
    HMM_STEPP(1); PREFETCH(1, O5);                                           \
    zl = dpp_add<0x143>(zl);                                                 \
    {                                                                        \
      float z   = rdlanef(zl, 63);                                           \
      float inv = __builtin_amdgcn_rcpf(z);                                  \
      float lg  = __logf(z);                                                 \
      HMM_STEPP(2); PREFETCH(2, O6);                                         \
      float2 invP = make_float2(inv, inv);                                   \
      float2 ep0 = pk_mul(eb[3][0], invP);                                   \
      float2 ep1 = pk_mul(eb[3][1], invP);                                   \
      float2 ep2 = pk_mul(eb[3][2], invP);                                   \
      float2 ep3 = pk_mul(eb[3][3], invP);                                   \
      float2 ep4 = pk_mul(eb[3][4], invP);                                   \
      HMM_COREP(ep0,ep1,ep2,ep3,ep4);                                        \
      PREFETCH(3, O7);                                                       \
      ll += lg;                                                              \
    }                                                                        \
    zl = LOCSUM();

// one wave per batch; no LDS; packed-f32 main loop
__global__ __launch_bounds__(64) void forward(
    const float* __restrict__ emisP, const float4* __restrict__ wIn2,
    const float* __restrict__ Ivec, const int* __restrict__ obs,
    float* __restrict__ out)
{
    const int l = threadIdx.x;
    const int b = blockIdx.x;
    const bool isl0 = (l == 0);
    const int* obp = obs + b * TT;

    // load per-state incoming weights, then build stride-5 pairs
    float2 W[5][4];
    {
        float4 w[10];
        #pragma unroll
        for (int k = 0; k < 10; ++k) w[k] = wIn2[10*l + k];
        #pragma unroll
        for (int j = 0; j < 5; ++j) {
            W[j][0] = make_float2(w[j].x, w[j+5].x);
            W[j][1] = make_float2(w[j].y, w[j+5].y);
            W[j][2] = make_float2(w[j].z, w[j+5].z);
            W[j][3] = make_float2(w[j].w, w[j+5].w);
        }
    }

    // obs ring: lane l of ovA holds obs[64k + l], ovB holds obs[64k+64 + l]
    int ovA = obp[l];
    int ovB = obp[64 + l];

    float2 p[5];
    float ll = 0.0f;
    float2 eb[4][5];

    // t = 0: states 0..3 (lane 0, lo halves of pairs 0..3) get I*emission
    {
        int o0 = rdlanei(ovA, 0);
        const float2* ep = (const float2*)(emisP + o0*SP + 10*l);
        float2 e0=ep[0], e1=ep[1], e2=ep[2], e3=ep[3];
        p[0] = make_float2(isl0 ? e0.x*Ivec[0] : 0.f, 0.f);
        p[1] = make_float2(isl0 ? e1.x*Ivec[1] : 0.f, 0.f);
        p[2] = make_float2(isl0 ? e2.x*Ivec[2] : 0.f, 0.f);
        p[3] = make_float2(isl0 ? e3.x*Ivec[3] : 0.f, 0.f);
        p[4] = make_float2(0.f, 0.f);
    }
    float zl = LOCSUM();   // z_0 partial; DPP tree runs inside first group

    // initial emission buffers: steps 1..4
    PREFETCH(0, rdlanei(ovA, 1));
    PREFETCH(1, rdlanei(ovA, 2));
    PREFETCH(2, rdlanei(ovA, 3));
    PREFETCH(3, rdlanei(ovA, 4));

    // superblocks: steps 64k+1 .. 64k+64, k = 0..126  (t = 1..8128)
    for (int kk = 0; kk < 127; ++kk) {
        int src = 64*kk + 128 + l;
        if (src >= TT) src = 0;            // clamped tail (value unused)
        int ovN = obp[src];
        #pragma unroll 1
        for (int j = 0; j < 7; ++j) {
            int base = 8*j + 5;
            GROUP(rdlanei(ovA,base  ), rdlanei(ovA,base+1),
                  rdlanei(ovA,base+2), rdlanei(ovA,base+3),
                  rdlanei(ovA,base+4), rdlanei(ovA,base+5),
                  rdlanei(ovA,base+6), rdlanei(ovA,base+7));
        }
        // j = 7 straddles the buffer boundary — compile-time lane indices
        GROUP(rdlanei(ovA,61), rdlanei(ovA,62), rdlanei(ovA,63),
              rdlanei(ovB,0),  rdlanei(ovB,1),  rdlanei(ovB,2),
              rdlanei(ovB,3),  rdlanei(ovB,4));
        ovA = ovB; ovB = ovN;
    }

    // epilogue groups: steps 8129..8184 (ovA covers [8128,8192))
    #pragma unroll 1
    for (int j = 0; j < 7; ++j) {
        int base = 8*j + 5;
        GROUP(rdlanei(ovA,base  ), rdlanei(ovA,base+1),
              rdlanei(ovA,base+2), rdlanei(ovA,base+3),
              rdlanei(ovA,base+4), rdlanei(ovA,base+5),
              rdlanei(ovA,base+6), rdlanei(ovA,base+7));
    }

    // final steps 8185..8191 (no renorm; final sum captures residual scale)
    HMM_STEPP(0); PREFETCH(0, rdlanei(ovA,61));
    HMM_STEPP(1); PREFETCH(1, rdlanei(ovA,62));
    HMM_STEPP(2); PREFETCH(2, rdlanei(ovA,63));
    HMM_STEPP(3);
    HMM_STEPP(0);
    HMM_STEPP(1);
    HMM_STEPP(2);

    {
        float zf = LOCSUM();
        zf = dpp_add<0x111>(zf);
        zf = dpp_add<0x112>(zf);
        zf = dpp_add<0x114>(zf);
        zf = dpp_add<0x118>(zf);
        zf = dpp_add<0x142>(zf);
        zf = dpp_add<0x143>(zf);
        ll += __logf(rdlanef(zf, 63));
    }
    if (isl0) out[b] = ll;
}

extern "C" void kernel_launch(void* const* d_in, const int* in_sizes, int n_in,
                              void* d_out, int out_size, void* d_ws, size_t ws_size,
                              hipStream_t stream)
{
    const float* x  = (const float*)d_in[0];   // inputs [32,8192,101]
    const float* ik = (const float*)d_in[1];   // init_kernel [4]
    const float* tk = (const float*)d_in[2];   // transition_kernel [1836]
    const float* ek = (const float*)d_in[3];   // emission_kernel [58656]
    float* out = (float*)d_out;

    char* ws = (char*)d_ws;
    float*  wIn2  = (float*)(ws + WIN_OFF);
    float*  Ivec  = (float*)(ws + IV_OFF);
    float*  emisP = (float*)(ws + EMIS_OFF);
    int*    obs   = (int*)(ws + OBS_OFF);

    hipLaunchKernelGGL(prep_tables, dim3(3), dim3(256), 0, stream, tk, ik, wIn2, Ivec);
    hipLaunchKernelGGL(prep_emis, dim3((100*SP + 255)/256), dim3(256), 0, stream, ek, emisP);
    hipLaunchKernelGGL(extract_obs, dim3((NB*TT + 3)/4), dim3(256), 0, stream, x, obs);
    hipLaunchKernelGGL(forward, dim3(NB), dim3(64), 0, stream,
                       emisP, (const float4*)wIn2, Ivec, obs, out);
}